// Round 3
// baseline (15639.085 us; speedup 1.0000x reference)
//
#include <hip/hip_runtime.h>

typedef unsigned short ushort_t;
typedef unsigned long long u64;
typedef __attribute__((ext_vector_type(8))) __bf16 bf16x8;
typedef __attribute__((ext_vector_type(4))) float f32x4;

#define B 256
#define TENC 512
#define TDEC 64
#define DIN 64
#define HD 512
#define OD 512
#define GG 256          // 16 batch-groups x 16 unit-groups
#define NGRP 16         // WGs per batch-group (unit-groups)
#define KTOT 576        // 512 (h) + 64 (x)
#define KI 18           // K iters of 32
#define NT 512          // threads per block

__device__ __forceinline__ float b2f(ushort_t v) {
  union { unsigned u; float f; } x; x.u = ((unsigned)v) << 16; return x.f;
}
__device__ __forceinline__ ushort_t f2b(float f) {
  union { float f; unsigned u; } x; x.f = f;
  unsigned r = x.u + 0x7fffu + ((x.u >> 16) & 1u);   // RNE
  return (ushort_t)(r >> 16);
}
__device__ __forceinline__ float sigmf(float x) { return 1.f / (1.f + __expf(-x)); }
__device__ __forceinline__ float tanhf_fast(float x) {
  float e = __expf(2.f * x);
  return 1.f - 2.f / (e + 1.f);
}
__device__ __forceinline__ float ld_elem(const void* p, size_t i, bool f32) {
  return f32 ? ((const float*)p)[i] : b2f(((const ushort_t*)p)[i]);
}
__device__ __forceinline__ bf16x8 cvt8(const float* f) {
  f32x4 u = *(const f32x4*)f, v = *(const f32x4*)(f + 4);
  bf16x8 r;
  r[0] = (__bf16)u[0]; r[1] = (__bf16)u[1]; r[2] = (__bf16)u[2]; r[3] = (__bf16)u[3];
  r[4] = (__bf16)v[0]; r[5] = (__bf16)v[1]; r[6] = (__bf16)v[2]; r[7] = (__bf16)v[3];
  return r;
}
// 16B device-coherent h load: two relaxed agent-scope u64 atomics (LLC).
__device__ __forceinline__ bf16x8 ld_h16(const ushort_t* p) {
  union { u64 q[2]; bf16x8 v; } x;
  x.q[0] = __hip_atomic_load((const u64*)p,     __ATOMIC_RELAXED, __HIP_MEMORY_SCOPE_AGENT);
  x.q[1] = __hip_atomic_load((const u64*)p + 1, __ATOMIC_RELAXED, __HIP_MEMORY_SCOPE_AGENT);
  return x.v;
}
// two u32 wave-step counters packed in a u64, both must be >= tgt
__device__ __forceinline__ bool flagok(u64 v, unsigned tgt) {
  return ((unsigned)v >= tgt) & ((unsigned)(v >> 32) >= tgt);
}

// ---------------------------------------------------------------------------
// Dtype probe (fp32 vs bf16 inputs) -> flag in d_ws.
// ---------------------------------------------------------------------------
__global__ void detect(const ushort_t* w, unsigned* flag) {
  if (threadIdx.x == 0) {
    unsigned f = 0;
    for (int i = 0; i < 128; ++i) {
      float v = b2f(w[i]);
      if (!(v * v < 1.f)) f = 1;    // catches NaN too
    }
    *flag = f;
  }
}

// ---------------------------------------------------------------------------
// Recurrent kernel, barrier-free per-wave dataflow.
//  bg = wg & 15 owns batch rows [bg*16, bg*16+16);
//  ug = wg >> 4 owns units [ug*32, ug*32+32) (x4 gates);
//  wave w owns units [ug*32+w*4, +4) x 4 gates (16x16 output tile).
// h layout: [ug 16][row 256][unit 32] bf16 -> each wave's A-fragment block is
// a fully-coalesced 1KB load, straight into registers (no LDS staging).
// Sync: per-WAVE u32 step counters, 8 packed per WG in a 32B line (128B
// spaced). Consumer polls its group's 16 lines (>= bstep) before loading h;
// producer release-stores its counter (drains h stores to LLC first).
// The entry poll also closes the double-buffer WAR: flags >= s  =>  every
// wave finished step s-1, including its reads of hbuf[(s-1)&1], which is
// exactly the buffer step s overwrites. NO __syncthreads in the step loop.
// ---------------------------------------------------------------------------
__global__ __launch_bounds__(NT, 1) void lstm_seq(
    const void* enc_inp, const void* dec_inp,
    const void* eWih, const void* eWhh, const void* ebih, const void* ebhh,
    const void* dWih, const void* dWhh, const void* dbih, const void* dbhh,
    ushort_t* hbuf0, ushort_t* hbuf1,
    unsigned* flags,
    void* dout, const unsigned* mode)
{
  __shared__ __align__(16) float Zs[8][16][20];  // per-wave z slab (wave-local only)
  __shared__ float Bias[128];

  const bool f32m = (*mode != 0);
  char* hid = (char*)dout + (size_t)B * TDEC * OD * (f32m ? 4 : 2);

  const int tid = threadIdx.x;
  const int lane = tid & 63;
  const int w = tid >> 6;
  const int wg = blockIdx.x;
  const int bg = wg & 15;          // batch group (members share XCD, perf only)
  const int ug = wg >> 4;          // unit group
  const int fm = lane & 15;
  const int q = lane >> 4;
  const int row0 = bg * 16;
  const int u0w = ug * 32 + w * 4;

  // cell-update lane mapping: one (row, unit) pair per lane, c in register
  const int crow = lane >> 2;
  const int cdu = lane & 3;
  float creg = 0.f;

  // flag addressing
  char* flgb = (char*)flags;
  const u64* pollp = (const u64*)(flgb + (size_t)((lane >> 2) * NGRP + bg) * 128
                                       + (size_t)(lane & 3) * 8);
  unsigned* myflag = (unsigned*)(flgb + (size_t)wg * 128 + (size_t)w * 4);

  // per-lane h-block offset (elements): block i adds i*B*32
  const size_t hoff = (size_t)(row0 + fm) * 32 + (size_t)q * 8;

  bf16x8 bfrag[KI];
  unsigned bstep = 0;

  for (int phase = 0; phase < 2; ++phase) {
    const void* Wih = phase ? dWih : eWih;
    const void* Whh = phase ? dWhh : eWhh;
    const void* bih = phase ? dbih : ebih;
    const void* bhh = phase ? dbhh : ebhh;
    const void* xin = phase ? dec_inp : enc_inp;
    const int T = phase ? TDEC : TENC;
    const int xstr = phase ? (TDEC * DIN) : (TENC * DIN);   // elements

    // per-wave weight fragments straight from global (once per phase)
    {
      const int grow = (fm >> 2) * HD + u0w + (fm & 3);
      for (int i = 0; i < KI; ++i) {
        union { ushort_t s[8]; bf16x8 v; } uf;
        const int k0 = i * 32 + q * 8;
#pragma unroll
        for (int e = 0; e < 8; ++e) {
          const int k = k0 + e;
          float wv = (k < HD) ? ld_elem(Whh, (size_t)grow * HD + k, f32m)
                              : ld_elem(Wih, (size_t)grow * DIN + (k - HD), f32m);
          uf.s[e] = f2b(wv);
        }
        bfrag[i] = uf.v;
      }
    }
    __syncthreads();   // all waves past last Bias read of previous phase
    if (tid < 128) {
      const int w_ = tid >> 4, n = tid & 15;
      const int grow = (n >> 2) * HD + ug * 32 + w_ * 4 + (n & 3);
      Bias[tid] = ld_elem(bih, grow, f32m) + ld_elem(bhh, grow, f32m);
    }
    __syncthreads();   // Bias ready

    for (int t = 0; t < T; ++t) {
      const ushort_t* hcur = (bstep & 1) ? hbuf1 : hbuf0;
      ushort_t* hnxt = (bstep & 1) ? hbuf0 : hbuf1;

      // ---- x-part first: independent of h, overlaps straggler wait ----
      f32x4 acca = {0.f, 0.f, 0.f, 0.f}, accb = {0.f, 0.f, 0.f, 0.f};
      if (!f32m) {
        const ushort_t* x0 = (const ushort_t*)xin + (size_t)(row0 + fm) * xstr + t * DIN;
        bf16x8 a0 = *(const bf16x8*)(x0 + q * 8);
        bf16x8 a1 = *(const bf16x8*)(x0 + 32 + q * 8);
        acca = __builtin_amdgcn_mfma_f32_16x16x32_bf16(a0, bfrag[16], acca, 0, 0, 0);
        accb = __builtin_amdgcn_mfma_f32_16x16x32_bf16(a1, bfrag[17], accb, 0, 0, 0);
      } else {
        const float* x0 = (const float*)xin + (size_t)(row0 + fm) * xstr + t * DIN;
        bf16x8 a0 = cvt8(x0 + q * 8);
        bf16x8 a1 = cvt8(x0 + 32 + q * 8);
        acca = __builtin_amdgcn_mfma_f32_16x16x32_bf16(a0, bfrag[16], acca, 0, 0, 0);
        accb = __builtin_amdgcn_mfma_f32_16x16x32_bf16(a1, bfrag[17], accb, 0, 0, 0);
      }

      // ---- poll: all 16 group flag-lines (8 waves each) >= bstep ----
      if (bstep) {
        u64 v = __hip_atomic_load(pollp, __ATOMIC_RELAXED, __HIP_MEMORY_SCOPE_AGENT);
        while (!__all(flagok(v, bstep))) {
          __builtin_amdgcn_s_sleep(1);
          v = __hip_atomic_load(pollp, __ATOMIC_RELAXED, __HIP_MEMORY_SCOPE_AGENT);
        }
      }

      // ---- load 16 A-blocks straight to registers (coalesced 1KB each) ----
      bf16x8 ah[16];
#pragma unroll
      for (int i = 0; i < 16; ++i)
        ah[i] = ld_h16(hcur + (size_t)i * (B * 32) + hoff);
#pragma unroll
      for (int i = 0; i < 16; i += 2) {
        acca = __builtin_amdgcn_mfma_f32_16x16x32_bf16(ah[i],     bfrag[i],     acca, 0, 0, 0);
        accb = __builtin_amdgcn_mfma_f32_16x16x32_bf16(ah[i + 1], bfrag[i + 1], accb, 0, 0, 0);
      }
      f32x4 acc = acca + accb;

      // z transpose via wave-private LDS slab (no cross-wave sync needed)
#pragma unroll
      for (int r = 0; r < 4; ++r)
        Zs[w][q * 4 + r][fm] = acc[r];
      __builtin_amdgcn_s_waitcnt(0);   // lgkmcnt(0): own wave's ds_writes done

      // cell update: lane -> (row = crow, unit = u0w + cdu)
      float h2;
      {
        const float* zr = Zs[w][crow];
        float zi = zr[cdu]      + Bias[w * 16 + cdu];
        float zf = zr[4 + cdu]  + Bias[w * 16 + 4 + cdu];
        float zg = zr[8 + cdu]  + Bias[w * 16 + 8 + cdu];
        float zo = zr[12 + cdu] + Bias[w * 16 + 12 + cdu];
        float c2 = sigmf(zf) * creg + sigmf(zi) * tanhf_fast(zg);
        h2 = sigmf(zo) * tanhf_fast(c2);
        creg = c2;
      }
      // pack (cdu, cdu+1) pairs, publish from even-cdu lanes
      float hn = __shfl_xor(h2, 1);
      unsigned pk = (unsigned)f2b(h2) | ((unsigned)f2b(hn) << 16);
      if ((cdu & 1) == 0) {
        __hip_atomic_store((unsigned*)(hnxt + (size_t)ug * (B * 32)
                                       + (size_t)(row0 + crow) * 32 + w * 4 + cdu),
                           pk, __ATOMIC_RELAXED, __HIP_MEMORY_SCOPE_AGENT);
      }
      // release: drains vmcnt (h stores AND this step's h loads), then flag
      if (lane == 0)
        __hip_atomic_store(myflag, bstep + 1, __ATOMIC_RELEASE, __HIP_MEMORY_SCOPE_AGENT);
      else
        __builtin_amdgcn_s_waitcnt(0x3f70);   // vmcnt(0) on non-flag lanes too

      // decoder hidden-state output: off the critical path (after publish)
      if (phase && (cdu & 1) == 0) {
        size_t off = ((size_t)(row0 + crow) * TDEC + t) * HD + u0w + cdu;
        if (f32m) {
          float2 f2; f2.x = h2; f2.y = hn;
          *(float2*)((float*)hid + off) = f2;
        } else {
          *(unsigned*)((ushort_t*)hid + off) = pk;
        }
      }
      ++bstep;
    }
  }
}

// ---------------------------------------------------------------------------
// Output projection: Y[16384x512] = Hd[16384x512] @ out_W^T + out_b.
// ---------------------------------------------------------------------------
__global__ __launch_bounds__(NT, 2) void out_proj(
    const void* Wo, const void* bo, void* dout, const unsigned* mode)
{
  __shared__ __align__(16) ushort_t Wc[16][520];
  const bool f32m = (*mode != 0);
  char* Ybase = (char*)dout;
  const char* Hd = Ybase + (size_t)B * TDEC * OD * (f32m ? 4 : 2);

  const int tid = threadIdx.x, lane = tid & 63, w = tid >> 6;
  const int fm = lane & 15, q = lane >> 4;
  const int nb = blockIdx.x & 31, mb = blockIdx.x >> 5;
  const int m0 = mb * 256, n0 = nb * 16;

  for (int idx = tid; idx < 16 * 512; idx += NT) {
    int n = idx >> 9, k = idx & 511;
    Wc[n][k] = f2b(ld_elem(Wo, (size_t)(n0 + n) * 512 + k, f32m));
  }
  __syncthreads();
  bf16x8 bfrag[16];
#pragma unroll
  for (int i = 0; i < 16; ++i) bfrag[i] = *(const bf16x8*)&Wc[fm][i * 32 + q * 8];

  f32x4 acc0 = {0.f, 0.f, 0.f, 0.f}, acc1 = {0.f, 0.f, 0.f, 0.f};
  if (!f32m) {
    const ushort_t* a0p = (const ushort_t*)Hd + (size_t)(m0 + w * 32 + fm) * 512;
    const ushort_t* a1p = (const ushort_t*)Hd + (size_t)(m0 + w * 32 + 16 + fm) * 512;
#pragma unroll
    for (int i = 0; i < 16; ++i) {
      int ko = i * 32 + q * 8;
      bf16x8 a0 = *(const bf16x8*)(a0p + ko);
      bf16x8 a1 = *(const bf16x8*)(a1p + ko);
      acc0 = __builtin_amdgcn_mfma_f32_16x16x32_bf16(a0, bfrag[i], acc0, 0, 0, 0);
      acc1 = __builtin_amdgcn_mfma_f32_16x16x32_bf16(a1, bfrag[i], acc1, 0, 0, 0);
    }
  } else {
    const float* a0p = (const float*)Hd + (size_t)(m0 + w * 32 + fm) * 512;
    const float* a1p = (const float*)Hd + (size_t)(m0 + w * 32 + 16 + fm) * 512;
#pragma unroll
    for (int i = 0; i < 16; ++i) {
      int ko = i * 32 + q * 8;
      bf16x8 a0 = cvt8(a0p + ko);
      bf16x8 a1 = cvt8(a1p + ko);
      acc0 = __builtin_amdgcn_mfma_f32_16x16x32_bf16(a0, bfrag[i], acc0, 0, 0, 0);
      acc1 = __builtin_amdgcn_mfma_f32_16x16x32_bf16(a1, bfrag[i], acc1, 0, 0, 0);
    }
  }
  float bias = ld_elem(bo, n0 + fm, f32m);
#pragma unroll
  for (int r = 0; r < 4; ++r) {
    size_t off0 = (size_t)(m0 + w * 32 + q * 4 + r) * 512 + n0 + fm;
    size_t off1 = off0 + (size_t)16 * 512;
    float v0 = acc0[r] + bias, v1 = acc1[r] + bias;
    if (f32m) { ((float*)Ybase)[off0] = v0; ((float*)Ybase)[off1] = v1; }
    else      { ((ushort_t*)Ybase)[off0] = f2b(v0); ((ushort_t*)Ybase)[off1] = f2b(v1); }
  }
}

extern "C" void kernel_launch(void* const* d_in, const int* in_sizes, int n_in,
                              void* d_out, int out_size, void* d_ws, size_t ws_size,
                              hipStream_t stream) {
  (void)in_sizes; (void)n_in; (void)out_size; (void)ws_size;
  const void* enc_inp = d_in[0];
  const void* dec_inp = d_in[1];
  const void* eWih = d_in[2];
  const void* eWhh = d_in[3];
  const void* ebih = d_in[4];
  const void* ebhh = d_in[5];
  const void* dWih = d_in[6];
  const void* dWhh = d_in[7];
  const void* dbih = d_in[8];
  const void* dbhh = d_in[9];
  const void* outW = d_in[10];
  const void* outb = d_in[11];

  unsigned* flag = (unsigned*)d_ws;

  // scratch inside the dec_outputs region of d_out (overwritten by out_proj):
  //   [128, 128+32K) : 256 per-WG flag lines, 128B apart (8 u32 per line)
  //   [64K, 64K+256K): hbuf0 (bf16)   [+256K..]: hbuf1
  char* ob = (char*)d_out;
  unsigned* flags = (unsigned*)(ob + 128);
  ushort_t* hbuf0 = (ushort_t*)(ob + 65536);
  ushort_t* hbuf1 = (ushort_t*)(ob + 65536 + (size_t)B * HD * 2);

  // zero flags/hbuf0 (initial h = 0); hbuf1 fully written at step 0
  hipMemsetAsync(d_out, 0, 65536 + (size_t)B * HD * 2, stream);

  detect<<<1, 64, 0, stream>>>((const ushort_t*)eWhh, flag);
  lstm_seq<<<GG, NT, 0, stream>>>(enc_inp, dec_inp, eWih, eWhh, ebih, ebhh,
                                  dWih, dWhh, dbih, dbhh,
                                  hbuf0, hbuf1, flags, d_out, flag);
  out_proj<<<dim3(64 * 32), NT, 0, stream>>>(outW, outb, d_out, flag);
}

// Round 4
// 11704.691 us; speedup vs baseline: 1.3361x; 1.3361x over previous
//
#include <hip/hip_runtime.h>

typedef unsigned short ushort_t;
typedef unsigned long long u64;
typedef __attribute__((ext_vector_type(8))) __bf16 bf16x8;
typedef __attribute__((ext_vector_type(4))) float f32x4;

#define B 256
#define TENC 512
#define TDEC 64
#define DIN 64
#define HD 512
#define OD 512
#define GG 256          // 16 batch-groups x 16 unit-groups
#define NGRP 16         // WGs per batch-group (unit-groups)
#define KTOT 576        // 512 (h) + 64 (x)
#define KI 18           // K iters of 32
#define NT 512          // threads per block

__device__ __forceinline__ float b2f(ushort_t v) {
  union { unsigned u; float f; } x; x.u = ((unsigned)v) << 16; return x.f;
}
__device__ __forceinline__ ushort_t f2b(float f) {
  union { float f; unsigned u; } x; x.f = f;
  unsigned r = x.u + 0x7fffu + ((x.u >> 16) & 1u);   // RNE
  return (ushort_t)(r >> 16);
}
__device__ __forceinline__ float sigmf(float x) { return 1.f / (1.f + __expf(-x)); }
__device__ __forceinline__ float tanhf_fast(float x) {
  float e = __expf(2.f * x);
  return 1.f - 2.f / (e + 1.f);
}
__device__ __forceinline__ float ld_elem(const void* p, size_t i, bool f32) {
  return f32 ? ((const float*)p)[i] : b2f(((const ushort_t*)p)[i]);
}
__device__ __forceinline__ bf16x8 cvt8(const float* f) {
  f32x4 u = *(const f32x4*)f, v = *(const f32x4*)(f + 4);
  bf16x8 r;
  r[0] = (__bf16)u[0]; r[1] = (__bf16)u[1]; r[2] = (__bf16)u[2]; r[3] = (__bf16)u[3];
  r[4] = (__bf16)v[0]; r[5] = (__bf16)v[1]; r[6] = (__bf16)v[2]; r[7] = (__bf16)v[3];
  return r;
}
// 16B device-coherent h load: two relaxed agent-scope u64 atomics (LLC).
__device__ __forceinline__ bf16x8 ld_h16(const ushort_t* p) {
  union { u64 q[2]; bf16x8 v; } x;
  x.q[0] = __hip_atomic_load((const u64*)p,     __ATOMIC_RELAXED, __HIP_MEMORY_SCOPE_AGENT);
  x.q[1] = __hip_atomic_load((const u64*)p + 1, __ATOMIC_RELAXED, __HIP_MEMORY_SCOPE_AGENT);
  return x.v;
}
// two u32 wave-step counters packed in a u64, both must be >= tgt
__device__ __forceinline__ bool flagok(u64 v, unsigned tgt) {
  return ((unsigned)v >= tgt) & ((unsigned)(v >> 32) >= tgt);
}

// ---------------------------------------------------------------------------
// Dtype probe (fp32 vs bf16 inputs) -> flag in d_ws.
// ---------------------------------------------------------------------------
__global__ void detect(const ushort_t* w, unsigned* flag) {
  if (threadIdx.x == 0) {
    unsigned f = 0;
    for (int i = 0; i < 128; ++i) {
      float v = b2f(w[i]);
      if (!(v * v < 1.f)) f = 1;    // catches NaN too
    }
    *flag = f;
  }
}

// ---------------------------------------------------------------------------
// Recurrent kernel (R2 decomposition, restructured step schedule).
//  bg = wg & 15 owns batch rows [bg*16, +16); ug = wg >> 4 owns units
//  [ug*32, +32) x 4 gates; wave w owns a 16x16 output tile.
// h layout: [ug 16][row 256][unit 32] bf16 (fully-coalesced staging).
// Step schedule: x-MFMA (h-independent) -> wave0 polls 16 group lines
// (8 waves each, 64 lanes, hot spin) -> sync -> stage h to LDS -> sync ->
// 16 h-MFMAs (dual acc chains) -> cell update (c in regs) -> h store ->
// per-WAVE release publish (own vmcnt drain only, no WG barrier) ->
// deferred hid store. 2 intra-WG barriers per step; 1 poller wave per WG.
// Poll(all flags >= s) also closes the hbuf WAR: publish at end of step
// s-1 comes after that wave's stage loads of hbuf[(s-1)&1] completed
// (release drains whole-wave vmcnt), the buffer step s overwrites.
// ---------------------------------------------------------------------------
__global__ __launch_bounds__(NT, 2) void lstm_seq(
    const void* enc_inp, const void* dec_inp,
    const void* eWih, const void* eWhh, const void* ebih, const void* ebhh,
    const void* dWih, const void* dWhh, const void* dbih, const void* dbhh,
    ushort_t* hbuf0, ushort_t* hbuf1,
    unsigned* flags,
    void* dout, const unsigned* mode)
{
  __shared__ __align__(16) char Hs[16384];       // staged h, XOR-swizzled
  __shared__ __align__(16) float Zs[8][16][20];  // per-wave z slab (wave-local)
  __shared__ float Bias[128];

  const bool f32m = (*mode != 0);
  char* hid = (char*)dout + (size_t)B * TDEC * OD * (f32m ? 4 : 2);

  const int tid = threadIdx.x;
  const int lane = tid & 63;
  const int w = tid >> 6;
  const int wg = blockIdx.x;
  const int bg = wg & 15;          // batch group (members share XCD, perf only)
  const int ug = wg >> 4;          // unit group
  const int fm = lane & 15;
  const int q = lane >> 4;
  const int row0 = bg * 16;
  const int u0w = ug * 32 + w * 4;

  // cell-update lane mapping: one (row, unit) pair per lane, c in register
  const int crow = lane >> 2;
  const int cdu = lane & 3;
  float creg = 0.f;

  // flag addressing: per-WG 128B line holding 8 per-wave u32 counters
  char* flgb = (char*)flags;
  const u64* pollp = (const u64*)(flgb + (size_t)((lane >> 2) * NGRP + bg) * 128
                                       + (size_t)(lane & 3) * 8);
  unsigned* myflag = (unsigned*)(flgb + (size_t)wg * 128 + (size_t)w * 4);

  bf16x8 bfrag[KI];
  unsigned bstep = 0;

  for (int phase = 0; phase < 2; ++phase) {
    const void* Wih = phase ? dWih : eWih;
    const void* Whh = phase ? dWhh : eWhh;
    const void* bih = phase ? dbih : ebih;
    const void* bhh = phase ? dbhh : ebhh;
    const void* xin = phase ? dec_inp : enc_inp;
    const int T = phase ? TDEC : TENC;
    const int xstr = phase ? (TDEC * DIN) : (TENC * DIN);   // elements

    // per-wave weight fragments straight from global (once per phase)
    {
      const int grow = (fm >> 2) * HD + u0w + (fm & 3);
      for (int i = 0; i < KI; ++i) {
        union { ushort_t s[8]; bf16x8 v; } uf;
        const int k0 = i * 32 + q * 8;
#pragma unroll
        for (int e = 0; e < 8; ++e) {
          const int k = k0 + e;
          float wv = (k < HD) ? ld_elem(Whh, (size_t)grow * HD + k, f32m)
                              : ld_elem(Wih, (size_t)grow * DIN + (k - HD), f32m);
          uf.s[e] = f2b(wv);
        }
        bfrag[i] = uf.v;
      }
    }
    __syncthreads();   // all waves past last Bias read of previous phase
    if (tid < 128) {
      const int w_ = tid >> 4, n = tid & 15;
      const int grow = (n >> 2) * HD + ug * 32 + w_ * 4 + (n & 3);
      Bias[tid] = ld_elem(bih, grow, f32m) + ld_elem(bhh, grow, f32m);
    }
    __syncthreads();   // Bias ready

    for (int t = 0; t < T; ++t) {
      const ushort_t* hcur = (bstep & 1) ? hbuf1 : hbuf0;
      ushort_t* hnxt = (bstep & 1) ? hbuf0 : hbuf1;

      // ---- x-part first (independent of h): fills the wait time ----
      f32x4 acca = {0.f, 0.f, 0.f, 0.f}, accb = {0.f, 0.f, 0.f, 0.f};
      if (!f32m) {
        const ushort_t* x0 = (const ushort_t*)xin + (size_t)(row0 + fm) * xstr + t * DIN;
        bf16x8 a0 = *(const bf16x8*)(x0 + q * 8);
        bf16x8 a1 = *(const bf16x8*)(x0 + 32 + q * 8);
        acca = __builtin_amdgcn_mfma_f32_16x16x32_bf16(a0, bfrag[16], acca, 0, 0, 0);
        accb = __builtin_amdgcn_mfma_f32_16x16x32_bf16(a1, bfrag[17], accb, 0, 0, 0);
      } else {
        const float* x0 = (const float*)xin + (size_t)(row0 + fm) * xstr + t * DIN;
        bf16x8 a0 = cvt8(x0 + q * 8);
        bf16x8 a1 = cvt8(x0 + 32 + q * 8);
        acca = __builtin_amdgcn_mfma_f32_16x16x32_bf16(a0, bfrag[16], acca, 0, 0, 0);
        accb = __builtin_amdgcn_mfma_f32_16x16x32_bf16(a1, bfrag[17], accb, 0, 0, 0);
      }

      // ---- poll: wave 0 only, 64 lanes cover 16 lines x 8 ctrs, hot spin ----
      if (bstep && w == 0) {
        u64 v = __hip_atomic_load(pollp, __ATOMIC_RELAXED, __HIP_MEMORY_SCOPE_AGENT);
        while (!__all(flagok(v, bstep)))
          v = __hip_atomic_load(pollp, __ATOMIC_RELAXED, __HIP_MEMORY_SCOPE_AGENT);
      }
      __syncthreads();   // releases all waves; orders prior Hs reads vs new writes

      // ---- stage h[row0..row0+16)[0..512) into LDS (16 KB, coalesced) ----
#pragma unroll
      for (int j = 0; j < 2; ++j) {
        const int o = (j * NT + tid) * 16;      // linear byte offset in region
        const int ks = o >> 10;                 // source unit-group block
        const int rem = o & 1023;               // row*64 + col*2
        const int r = rem >> 6;
        const int od = o ^ ((r & 7) << 4);      // bank-conflict swizzle
        *(bf16x8*)(Hs + od) =
            ld_h16(hcur + (size_t)ks * (B * 32) + (size_t)row0 * 32 + (rem >> 1));
      }
      __syncthreads();   // Hs ready

      // ---- 16 h-MFMAs, dual accumulator chains ----
      const int sw = (fm & 7) << 4;
#pragma unroll
      for (int i = 0; i < 16; i += 2) {
        bf16x8 a0 = *(const bf16x8*)(Hs + ((i * 1024 + fm * 64 + q * 16) ^ sw));
        bf16x8 a1 = *(const bf16x8*)(Hs + (((i + 1) * 1024 + fm * 64 + q * 16) ^ sw));
        acca = __builtin_amdgcn_mfma_f32_16x16x32_bf16(a0, bfrag[i],     acca, 0, 0, 0);
        accb = __builtin_amdgcn_mfma_f32_16x16x32_bf16(a1, bfrag[i + 1], accb, 0, 0, 0);
      }
      f32x4 acc = acca + accb;

      // z -> wave-private LDS slab; C/D layout: col=fm, row=q*4+r
#pragma unroll
      for (int r = 0; r < 4; ++r)
        Zs[w][q * 4 + r][fm] = acc[r];

      // cell update: lane -> (row = crow, unit = u0w + cdu); c in register
      float h2;
      {
        const float* zr = Zs[w][crow];
        float zi = zr[cdu]      + Bias[w * 16 + cdu];
        float zf = zr[4 + cdu]  + Bias[w * 16 + 4 + cdu];
        float zg = zr[8 + cdu]  + Bias[w * 16 + 8 + cdu];
        float zo = zr[12 + cdu] + Bias[w * 16 + 12 + cdu];
        float c2 = sigmf(zf) * creg + sigmf(zi) * tanhf_fast(zg);
        h2 = sigmf(zo) * tanhf_fast(c2);
        creg = c2;
      }
      // pack (cdu, cdu+1) pairs, publish h from even-cdu lanes
      float hn = __shfl_xor(h2, 1);
      unsigned pk = (unsigned)f2b(h2) | ((unsigned)f2b(hn) << 16);
      if ((cdu & 1) == 0) {
        __hip_atomic_store((unsigned*)(hnxt + (size_t)ug * (B * 32)
                                       + (size_t)(row0 + crow) * 32 + w * 4 + cdu),
                           pk, __ATOMIC_RELAXED, __HIP_MEMORY_SCOPE_AGENT);
      }
      // per-WAVE publish: release drains this wave's vmcnt (h stores AND this
      // step's stage loads), then the flag becomes visible
      if (lane == 0)
        __hip_atomic_store(myflag, bstep + 1, __ATOMIC_RELEASE, __HIP_MEMORY_SCOPE_AGENT);

      // decoder hidden-state output: deferred until after publish
      if (phase && (cdu & 1) == 0) {
        size_t off = ((size_t)(row0 + crow) * TDEC + t) * HD + u0w + cdu;
        if (f32m) {
          float2 f2; f2.x = h2; f2.y = hn;
          *(float2*)((float*)hid + off) = f2;
        } else {
          *(unsigned*)((ushort_t*)hid + off) = pk;
        }
      }
      ++bstep;
    }
  }
}

// ---------------------------------------------------------------------------
// Output projection: Y[16384x512] = Hd[16384x512] @ out_W^T + out_b.
// ---------------------------------------------------------------------------
__global__ __launch_bounds__(NT, 2) void out_proj(
    const void* Wo, const void* bo, void* dout, const unsigned* mode)
{
  __shared__ __align__(16) ushort_t Wc[16][520];
  const bool f32m = (*mode != 0);
  char* Ybase = (char*)dout;
  const char* Hd = Ybase + (size_t)B * TDEC * OD * (f32m ? 4 : 2);

  const int tid = threadIdx.x, lane = tid & 63, w = tid >> 6;
  const int fm = lane & 15, q = lane >> 4;
  const int nb = blockIdx.x & 31, mb = blockIdx.x >> 5;
  const int m0 = mb * 256, n0 = nb * 16;

  for (int idx = tid; idx < 16 * 512; idx += NT) {
    int n = idx >> 9, k = idx & 511;
    Wc[n][k] = f2b(ld_elem(Wo, (size_t)(n0 + n) * 512 + k, f32m));
  }
  __syncthreads();
  bf16x8 bfrag[16];
#pragma unroll
  for (int i = 0; i < 16; ++i) bfrag[i] = *(const bf16x8*)&Wc[fm][i * 32 + q * 8];

  f32x4 acc0 = {0.f, 0.f, 0.f, 0.f}, acc1 = {0.f, 0.f, 0.f, 0.f};
  if (!f32m) {
    const ushort_t* a0p = (const ushort_t*)Hd + (size_t)(m0 + w * 32 + fm) * 512;
    const ushort_t* a1p = (const ushort_t*)Hd + (size_t)(m0 + w * 32 + 16 + fm) * 512;
#pragma unroll
    for (int i = 0; i < 16; ++i) {
      int ko = i * 32 + q * 8;
      bf16x8 a0 = *(const bf16x8*)(a0p + ko);
      bf16x8 a1 = *(const bf16x8*)(a1p + ko);
      acc0 = __builtin_amdgcn_mfma_f32_16x16x32_bf16(a0, bfrag[i], acc0, 0, 0, 0);
      acc1 = __builtin_amdgcn_mfma_f32_16x16x32_bf16(a1, bfrag[i], acc1, 0, 0, 0);
    }
  } else {
    const float* a0p = (const float*)Hd + (size_t)(m0 + w * 32 + fm) * 512;
    const float* a1p = (const float*)Hd + (size_t)(m0 + w * 32 + 16 + fm) * 512;
#pragma unroll
    for (int i = 0; i < 16; ++i) {
      int ko = i * 32 + q * 8;
      bf16x8 a0 = cvt8(a0p + ko);
      bf16x8 a1 = cvt8(a1p + ko);
      acc0 = __builtin_amdgcn_mfma_f32_16x16x32_bf16(a0, bfrag[i], acc0, 0, 0, 0);
      acc1 = __builtin_amdgcn_mfma_f32_16x16x32_bf16(a1, bfrag[i], acc1, 0, 0, 0);
    }
  }
  float bias = ld_elem(bo, n0 + fm, f32m);
#pragma unroll
  for (int r = 0; r < 4; ++r) {
    size_t off0 = (size_t)(m0 + w * 32 + q * 4 + r) * 512 + n0 + fm;
    size_t off1 = off0 + (size_t)16 * 512;
    float v0 = acc0[r] + bias, v1 = acc1[r] + bias;
    if (f32m) { ((float*)Ybase)[off0] = v0; ((float*)Ybase)[off1] = v1; }
    else      { ((ushort_t*)Ybase)[off0] = f2b(v0); ((ushort_t*)Ybase)[off1] = f2b(v1); }
  }
}

extern "C" void kernel_launch(void* const* d_in, const int* in_sizes, int n_in,
                              void* d_out, int out_size, void* d_ws, size_t ws_size,
                              hipStream_t stream) {
  (void)in_sizes; (void)n_in; (void)out_size; (void)ws_size;
  const void* enc_inp = d_in[0];
  const void* dec_inp = d_in[1];
  const void* eWih = d_in[2];
  const void* eWhh = d_in[3];
  const void* ebih = d_in[4];
  const void* ebhh = d_in[5];
  const void* dWih = d_in[6];
  const void* dWhh = d_in[7];
  const void* dbih = d_in[8];
  const void* dbhh = d_in[9];
  const void* outW = d_in[10];
  const void* outb = d_in[11];

  unsigned* flag = (unsigned*)d_ws;

  // scratch inside the dec_outputs region of d_out (overwritten by out_proj):
  //   [128, 128+32K) : 256 per-WG flag lines, 128B apart (8 u32 per line)
  //   [64K, 64K+256K): hbuf0 (bf16)   [+256K..]: hbuf1
  char* ob = (char*)d_out;
  unsigned* flags = (unsigned*)(ob + 128);
  ushort_t* hbuf0 = (ushort_t*)(ob + 65536);
  ushort_t* hbuf1 = (ushort_t*)(ob + 65536 + (size_t)B * HD * 2);

  // zero flags/hbuf0 (initial h = 0); hbuf1 fully written at step 0
  hipMemsetAsync(d_out, 0, 65536 + (size_t)B * HD * 2, stream);

  detect<<<1, 64, 0, stream>>>((const ushort_t*)eWhh, flag);
  lstm_seq<<<GG, NT, 0, stream>>>(enc_inp, dec_inp, eWih, eWhh, ebih, ebhh,
                                  dWih, dWhh, dbih, dbhh,
                                  hbuf0, hbuf1, flags, d_out, flag);
  out_proj<<<dim3(64 * 32), NT, 0, stream>>>(outW, outb, d_out, flag);
}

// Round 5
// 2146.017 us; speedup vs baseline: 7.2875x; 5.4541x over previous
//
#include <hip/hip_runtime.h>

typedef unsigned short ushort_t;
typedef unsigned long long u64;
typedef __attribute__((ext_vector_type(8))) __bf16 bf16x8;
typedef __attribute__((ext_vector_type(4))) float f32x4;

#define B 256
#define TENC 512
#define TDEC 64
#define DIN 64
#define HD 512
#define OD 512
#define GG 256          // 16 batch-groups x 16 unit-groups
#define NGRP 16         // WGs per batch-group (unit-groups)
#define KTOT 576        // 512 (h) + 64 (x)
#define KI 18           // K iters of 32
#define NT 512          // threads per block

__device__ __forceinline__ float b2f(ushort_t v) {
  union { unsigned u; float f; } x; x.u = ((unsigned)v) << 16; return x.f;
}
__device__ __forceinline__ ushort_t f2b(float f) {
  union { float f; unsigned u; } x; x.f = f;
  unsigned r = x.u + 0x7fffu + ((x.u >> 16) & 1u);   // RNE
  return (ushort_t)(r >> 16);
}
__device__ __forceinline__ float sigmf(float x) { return 1.f / (1.f + __expf(-x)); }
__device__ __forceinline__ float tanhf_fast(float x) {
  float e = __expf(2.f * x);
  return 1.f - 2.f / (e + 1.f);
}
__device__ __forceinline__ float ld_elem(const void* p, size_t i, bool f32) {
  return f32 ? ((const float*)p)[i] : b2f(((const ushort_t*)p)[i]);
}
__device__ __forceinline__ bf16x8 cvt8(const float* f) {
  f32x4 u = *(const f32x4*)f, v = *(const f32x4*)(f + 4);
  bf16x8 r;
  r[0] = (__bf16)u[0]; r[1] = (__bf16)u[1]; r[2] = (__bf16)u[2]; r[3] = (__bf16)u[3];
  r[4] = (__bf16)v[0]; r[5] = (__bf16)v[1]; r[6] = (__bf16)v[2]; r[7] = (__bf16)v[3];
  return r;
}
// 16B device-coherent h load: two relaxed agent-scope u64 atomics (LLC).
__device__ __forceinline__ bf16x8 ld_h16(const ushort_t* p) {
  union { u64 q[2]; bf16x8 v; } x;
  x.q[0] = __hip_atomic_load((const u64*)p,     __ATOMIC_RELAXED, __HIP_MEMORY_SCOPE_AGENT);
  x.q[1] = __hip_atomic_load((const u64*)p + 1, __ATOMIC_RELAXED, __HIP_MEMORY_SCOPE_AGENT);
  return x.v;
}

// ---------------------------------------------------------------------------
// Dtype probe (fp32 vs bf16 inputs) -> flag in d_ws.
// ---------------------------------------------------------------------------
__global__ void detect(const ushort_t* w, unsigned* flag) {
  if (threadIdx.x == 0) {
    unsigned f = 0;
    for (int i = 0; i < 128; ++i) {
      float v = b2f(w[i]);
      if (!(v * v < 1.f)) f = 1;    // catches NaN too
    }
    *flag = f;
  }
}

// ---------------------------------------------------------------------------
// Recurrent kernel — R2's PROVEN sync skeleton (relaxed sc1 stores only,
// WG-level flag published by tid0 after a drain barrier, 16-lane paced poll),
// with compute-local scheduling improvements:
//   * x-MFMAs hoisted to the top of the step (overlap straggler wait)
//   * dual accumulator chains for the 16 h-MFMAs
//   * decoder hid store deferred until after the flag publish
// NO acquire/release at agent scope anywhere in the step loop.
//  bg = wg & 15 owns batch rows [bg*16,+16); ug = wg >> 4 owns units
//  [ug*32,+32) x 4 gates; wave w owns a 16x16 output tile.
// h layout: [ug 16][row 256][unit 32] bf16 (coalesced both sides).
// Poll(all group flags >= s) closes the hbuf WAR: a flag = s publish
// happened after that WG's drain barrier (vmcnt 0 => its step s-1 stage
// loads of hbuf[(s-1)&1] completed), which is the buffer step s+1 rewrites.
// ---------------------------------------------------------------------------
__global__ __launch_bounds__(NT, 2) void lstm_seq(
    const void* enc_inp, const void* dec_inp,
    const void* eWih, const void* eWhh, const void* ebih, const void* ebhh,
    const void* dWih, const void* dWhh, const void* dbih, const void* dbhh,
    ushort_t* hbuf0, ushort_t* hbuf1,
    unsigned* flags,
    void* dout, const unsigned* mode)
{
  __shared__ __align__(16) char Hs[16384];       // staged h, XOR-swizzled
  __shared__ __align__(16) float Zs[8][16][20];  // per-wave z slab (wave-local)
  __shared__ float Bias[128];

  const bool f32m = (*mode != 0);
  char* hid = (char*)dout + (size_t)B * TDEC * OD * (f32m ? 4 : 2);

  const int tid = threadIdx.x;
  const int lane = tid & 63;
  const int w = tid >> 6;
  const int wg = blockIdx.x;
  const int bg = wg & 15;          // batch group (members share XCD, perf only)
  const int ug = wg >> 4;          // unit group
  const int fm = lane & 15;
  const int q = lane >> 4;
  const int row0 = bg * 16;
  const int u0w = ug * 32 + w * 4;

  // cell-update lane mapping: one (row, unit) pair per lane, c in register
  const int crow = lane >> 2;
  const int cdu = lane & 3;
  float creg = 0.f;

  bf16x8 bfrag[KI];
  unsigned bstep = 0;

  for (int phase = 0; phase < 2; ++phase) {
    const void* Wih = phase ? dWih : eWih;
    const void* Whh = phase ? dWhh : eWhh;
    const void* bih = phase ? dbih : ebih;
    const void* bhh = phase ? dbhh : ebhh;
    const void* xin = phase ? dec_inp : enc_inp;
    const int T = phase ? TDEC : TENC;
    const int xstr = phase ? (TDEC * DIN) : (TENC * DIN);   // elements

    // per-wave weight fragments straight from global (once per phase)
    {
      const int grow = (fm >> 2) * HD + u0w + (fm & 3);
      for (int i = 0; i < KI; ++i) {
        union { ushort_t s[8]; bf16x8 v; } uf;
        const int k0 = i * 32 + q * 8;
#pragma unroll
        for (int e = 0; e < 8; ++e) {
          const int k = k0 + e;
          float wv = (k < HD) ? ld_elem(Whh, (size_t)grow * HD + k, f32m)
                              : ld_elem(Wih, (size_t)grow * DIN + (k - HD), f32m);
          uf.s[e] = f2b(wv);
        }
        bfrag[i] = uf.v;
      }
    }
    __syncthreads();   // all waves past last Bias read of previous phase
    if (tid < 128) {
      const int w_ = tid >> 4, n = tid & 15;
      const int grow = (n >> 2) * HD + ug * 32 + w_ * 4 + (n & 3);
      Bias[tid] = ld_elem(bih, grow, f32m) + ld_elem(bhh, grow, f32m);
    }
    __syncthreads();   // Bias ready

    for (int t = 0; t < T; ++t) {
      const ushort_t* hcur = (bstep & 1) ? hbuf1 : hbuf0;
      ushort_t* hnxt = (bstep & 1) ? hbuf0 : hbuf1;

      // ---- x-part first (independent of h): overlaps the straggler wait ----
      f32x4 acca = {0.f, 0.f, 0.f, 0.f}, accb = {0.f, 0.f, 0.f, 0.f};
      if (!f32m) {
        const ushort_t* x0 = (const ushort_t*)xin + (size_t)(row0 + fm) * xstr + t * DIN;
        bf16x8 a0 = *(const bf16x8*)(x0 + q * 8);
        bf16x8 a1 = *(const bf16x8*)(x0 + 32 + q * 8);
        acca = __builtin_amdgcn_mfma_f32_16x16x32_bf16(a0, bfrag[16], acca, 0, 0, 0);
        accb = __builtin_amdgcn_mfma_f32_16x16x32_bf16(a1, bfrag[17], accb, 0, 0, 0);
      } else {
        const float* x0 = (const float*)xin + (size_t)(row0 + fm) * xstr + t * DIN;
        bf16x8 a0 = cvt8(x0 + q * 8);
        bf16x8 a1 = cvt8(x0 + 32 + q * 8);
        acca = __builtin_amdgcn_mfma_f32_16x16x32_bf16(a0, bfrag[16], acca, 0, 0, 0);
        accb = __builtin_amdgcn_mfma_f32_16x16x32_bf16(a1, bfrag[17], accb, 0, 0, 0);
      }

      // ---- poll (R2-proven): 16 lanes of wave 0, paced with s_sleep ----
      if (bstep && tid < NGRP) {
        // group members are wgs {bg + g*16 : g = 0..15}
        while (__hip_atomic_load(&flags[(bg + tid * 16) * 32],
                                 __ATOMIC_RELAXED, __HIP_MEMORY_SCOPE_AGENT) < bstep)
          __builtin_amdgcn_s_sleep(1);
      }
      __syncthreads();   // gate: all group flags >= bstep confirmed

      // ---- stage h[row0..row0+16)[0..512) into LDS (16 KB, coalesced) ----
#pragma unroll
      for (int j = 0; j < 2; ++j) {
        const int o = (j * NT + tid) * 16;      // linear byte offset in region
        const int ks = o >> 10;                 // source unit-group block
        const int rem = o & 1023;               // row*64 + col*2
        const int r = rem >> 6;
        const int od = o ^ ((r & 7) << 4);      // bank-conflict swizzle
        *(bf16x8*)(Hs + od) =
            ld_h16(hcur + (size_t)ks * (B * 32) + (size_t)row0 * 32 + (rem >> 1));
      }
      __syncthreads();   // Hs ready

      // ---- 16 h-MFMAs, dual accumulator chains ----
      const int sw = (fm & 7) << 4;
#pragma unroll
      for (int i = 0; i < 16; i += 2) {
        bf16x8 a0 = *(const bf16x8*)(Hs + ((i * 1024 + fm * 64 + q * 16) ^ sw));
        bf16x8 a1 = *(const bf16x8*)(Hs + (((i + 1) * 1024 + fm * 64 + q * 16) ^ sw));
        acca = __builtin_amdgcn_mfma_f32_16x16x32_bf16(a0, bfrag[i],     acca, 0, 0, 0);
        accb = __builtin_amdgcn_mfma_f32_16x16x32_bf16(a1, bfrag[i + 1], accb, 0, 0, 0);
      }
      f32x4 acc = acca + accb;

      // z -> wave-private LDS slab; C/D layout: col=fm, row=q*4+r
#pragma unroll
      for (int r = 0; r < 4; ++r)
        Zs[w][q * 4 + r][fm] = acc[r];

      // cell update: lane -> (row = crow, unit = u0w + cdu); c in register
      float h2;
      {
        const float* zr = Zs[w][crow];
        float zi = zr[cdu]      + Bias[w * 16 + cdu];
        float zf = zr[4 + cdu]  + Bias[w * 16 + 4 + cdu];
        float zg = zr[8 + cdu]  + Bias[w * 16 + 8 + cdu];
        float zo = zr[12 + cdu] + Bias[w * 16 + 12 + cdu];
        float c2 = sigmf(zf) * creg + sigmf(zi) * tanhf_fast(zg);
        h2 = sigmf(zo) * tanhf_fast(c2);
        creg = c2;
      }
      // pack (cdu, cdu+1) pairs, publish h from even-cdu lanes (relaxed sc1)
      float hn = __shfl_xor(h2, 1);
      unsigned pk = (unsigned)f2b(h2) | ((unsigned)f2b(hn) << 16);
      if ((cdu & 1) == 0) {
        __hip_atomic_store((unsigned*)(hnxt + (size_t)ug * (B * 32)
                                       + (size_t)(row0 + crow) * 32 + w * 4 + cdu),
                           pk, __ATOMIC_RELAXED, __HIP_MEMORY_SCOPE_AGENT);
      }

      // ---- drain + WG-level publish (R2-proven; no release anywhere) ----
      __syncthreads();                 // compiler emits s_waitcnt vmcnt(0) first
      if (tid == 0)
        __hip_atomic_store(&flags[wg * 32], bstep + 1,
                           __ATOMIC_RELAXED, __HIP_MEMORY_SCOPE_AGENT);

      // decoder hidden-state output: deferred until after publish
      if (phase && (cdu & 1) == 0) {
        size_t off = ((size_t)(row0 + crow) * TDEC + t) * HD + u0w + cdu;
        if (f32m) {
          float2 f2; f2.x = h2; f2.y = hn;
          *(float2*)((float*)hid + off) = f2;
        } else {
          *(unsigned*)((ushort_t*)hid + off) = pk;
        }
      }
      ++bstep;
    }
  }
}

// ---------------------------------------------------------------------------
// Output projection: Y[16384x512] = Hd[16384x512] @ out_W^T + out_b.
// ---------------------------------------------------------------------------
__global__ __launch_bounds__(NT, 2) void out_proj(
    const void* Wo, const void* bo, void* dout, const unsigned* mode)
{
  __shared__ __align__(16) ushort_t Wc[16][520];
  const bool f32m = (*mode != 0);
  char* Ybase = (char*)dout;
  const char* Hd = Ybase + (size_t)B * TDEC * OD * (f32m ? 4 : 2);

  const int tid = threadIdx.x, lane = tid & 63, w = tid >> 6;
  const int fm = lane & 15, q = lane >> 4;
  const int nb = blockIdx.x & 31, mb = blockIdx.x >> 5;
  const int m0 = mb * 256, n0 = nb * 16;

  for (int idx = tid; idx < 16 * 512; idx += NT) {
    int n = idx >> 9, k = idx & 511;
    Wc[n][k] = f2b(ld_elem(Wo, (size_t)(n0 + n) * 512 + k, f32m));
  }
  __syncthreads();
  bf16x8 bfrag[16];
#pragma unroll
  for (int i = 0; i < 16; ++i) bfrag[i] = *(const bf16x8*)&Wc[fm][i * 32 + q * 8];

  f32x4 acc0 = {0.f, 0.f, 0.f, 0.f}, acc1 = {0.f, 0.f, 0.f, 0.f};
  if (!f32m) {
    const ushort_t* a0p = (const ushort_t*)Hd + (size_t)(m0 + w * 32 + fm) * 512;
    const ushort_t* a1p = (const ushort_t*)Hd + (size_t)(m0 + w * 32 + 16 + fm) * 512;
#pragma unroll
    for (int i = 0; i < 16; ++i) {
      int ko = i * 32 + q * 8;
      bf16x8 a0 = *(const bf16x8*)(a0p + ko);
      bf16x8 a1 = *(const bf16x8*)(a1p + ko);
      acc0 = __builtin_amdgcn_mfma_f32_16x16x32_bf16(a0, bfrag[i], acc0, 0, 0, 0);
      acc1 = __builtin_amdgcn_mfma_f32_16x16x32_bf16(a1, bfrag[i], acc1, 0, 0, 0);
    }
  } else {
    const float* a0p = (const float*)Hd + (size_t)(m0 + w * 32 + fm) * 512;
    const float* a1p = (const float*)Hd + (size_t)(m0 + w * 32 + 16 + fm) * 512;
#pragma unroll
    for (int i = 0; i < 16; ++i) {
      int ko = i * 32 + q * 8;
      bf16x8 a0 = cvt8(a0p + ko);
      bf16x8 a1 = cvt8(a1p + ko);
      acc0 = __builtin_amdgcn_mfma_f32_16x16x32_bf16(a0, bfrag[i], acc0, 0, 0, 0);
      acc1 = __builtin_amdgcn_mfma_f32_16x16x32_bf16(a1, bfrag[i], acc1, 0, 0, 0);
    }
  }
  float bias = ld_elem(bo, n0 + fm, f32m);
#pragma unroll
  for (int r = 0; r < 4; ++r) {
    size_t off0 = (size_t)(m0 + w * 32 + q * 4 + r) * 512 + n0 + fm;
    size_t off1 = off0 + (size_t)16 * 512;
    float v0 = acc0[r] + bias, v1 = acc1[r] + bias;
    if (f32m) { ((float*)Ybase)[off0] = v0; ((float*)Ybase)[off1] = v1; }
    else      { ((ushort_t*)Ybase)[off0] = f2b(v0); ((ushort_t*)Ybase)[off1] = f2b(v1); }
  }
}

extern "C" void kernel_launch(void* const* d_in, const int* in_sizes, int n_in,
                              void* d_out, int out_size, void* d_ws, size_t ws_size,
                              hipStream_t stream) {
  (void)in_sizes; (void)n_in; (void)out_size; (void)ws_size;
  const void* enc_inp = d_in[0];
  const void* dec_inp = d_in[1];
  const void* eWih = d_in[2];
  const void* eWhh = d_in[3];
  const void* ebih = d_in[4];
  const void* ebhh = d_in[5];
  const void* dWih = d_in[6];
  const void* dWhh = d_in[7];
  const void* dbih = d_in[8];
  const void* dbhh = d_in[9];
  const void* outW = d_in[10];
  const void* outb = d_in[11];

  unsigned* flag = (unsigned*)d_ws;

  // scratch inside the dec_outputs region of d_out (overwritten by out_proj):
  //   [128, 128+32K) : 256 WG flag lines, 128B apart (1 u32 each)
  //   [64K, 64K+256K): hbuf0 (bf16)   [+256K..]: hbuf1
  char* ob = (char*)d_out;
  unsigned* flags = (unsigned*)(ob + 128);
  ushort_t* hbuf0 = (ushort_t*)(ob + 65536);
  ushort_t* hbuf1 = (ushort_t*)(ob + 65536 + (size_t)B * HD * 2);

  // zero flags/hbuf0 (initial h = 0); hbuf1 fully written at step 0
  hipMemsetAsync(d_out, 0, 65536 + (size_t)B * HD * 2, stream);

  detect<<<1, 64, 0, stream>>>((const ushort_t*)eWhh, flag);
  lstm_seq<<<GG, NT, 0, stream>>>(enc_inp, dec_inp, eWih, eWhh, ebih, ebhh,
                                  dWih, dWhh, dbih, dbhh,
                                  hbuf0, hbuf1, flags, d_out, flag);
  out_proj<<<dim3(64 * 32), NT, 0, stream>>>(outW, outb, d_out, flag);
}